// Round 4
// baseline (37.564 us; speedup 1.0000x reference)
//
#include <hip/hip_runtime.h>
#include <math.h>

typedef float v2f __attribute__((ext_vector_type(2)));

constexpr int NW = 14;
constexpr int DIM = 1 << NW;      // 16384
constexpr int BATCH = 256;
constexpr int NT = 512;           // 8 waves; 32 amps/thread as 16 v2f pairs

// Swizzle: fold bits 5..9 AND bits 10..13 into the 5 bank bits.
// Linear over XOR => swz(base|off) = swz(base) ^ swz(off) for disjoint bits.
// Per-phase lane->bank maps all have rank 5 => <=2 lanes/bank (free).
__device__ __host__ constexpr int swzc(int i) {
    return i ^ ((i >> 5) & 31) ^ (((i >> 10) & 15) << 1);
}

// Scatter t bits 0..8 to global positions Q0..Q8 (Q0..Q3 = lane bits 0-3,
// Q4 = lane bit 4 (permlane16 slot), Q5 = lane bit 5 (permlane32 slot),
// Q6..Q8 = wave bits).
template<int Q0,int Q1,int Q2,int Q3,int Q4,int Q5,int Q6,int Q7,int Q8>
__device__ __forceinline__ int scat9(int t) {
    return ((t & 1) << Q0) | (((t >> 1) & 1) << Q1) | (((t >> 2) & 1) << Q2) |
           (((t >> 3) & 1) << Q3) | (((t >> 4) & 1) << Q4) | (((t >> 5) & 1) << Q5) |
           (((t >> 6) & 1) << Q6) | (((t >> 7) & 1) << Q7) | (((t >> 8) & 1) << Q8);
}

// ---------------------------------------------------------------------------
// Uniform packed gate: wire/target = slot bits JW, JT; packed dim spectator.
template<int JW, int JT>
__device__ __forceinline__ void gate_u(v2f (&pr)[16], v2f (&pi)[16],
                                       float cy, float sy, float c1, float s1,
                                       float cx, float sx)
{
    constexpr int BW = 1 << JW, BT = 1 << JT;
    #pragma unroll
    for (int m = 0; m < 4; ++m) {
        int l00 = 0, mm = m;
        #pragma unroll
        for (int j = 0; j < 4; ++j)
            if (j != JW && j != JT) { l00 |= (mm & 1) << j; mm >>= 1; }
        const int iA = l00, iB = l00 | BW, iC = l00 | BT, iD = l00 | BW | BT;

        v2f a00r = pr[iA], a00i = pi[iA];
        v2f a10r = pr[iB], a10i = pi[iB];
        v2f a01r = pr[iC], a01i = pi[iC];
        v2f a11r = pr[iD], a11i = pi[iD];

        v2f v0r = cy*a00r - sy*a10r, v0i = cy*a00i - sy*a10i;
        v2f v1r = sy*a00r + cy*a10r, v1i = sy*a00i + cy*a10i;
        v2f u0r = cy*a01r - sy*a11r, u0i = cy*a01i - sy*a11i;
        v2f u1r = sy*a01r + cy*a11r, u1i = sy*a01i + cy*a11i;

        v2f b00r = c1*v0r + s1*v0i, b00i = c1*v0i - s1*v0r;
        v2f b10r = c1*v1r - s1*v1i, b10i = c1*v1i + s1*v1r;
        v2f b01r = c1*u0r + s1*u0i, b01i = c1*u0i - s1*u0r;
        v2f b11r = c1*u1r - s1*u1i, b11i = c1*u1i + s1*u1r;

        v2f o00r = cx*b00r + sx*b11i, o00i = cx*b00i - sx*b11r;
        v2f o10r = sx*b00i + cx*b11r, o10i = cx*b11i - sx*b00r;
        v2f o01r = cx*b01r + sx*b10i, o01i = cx*b01i - sx*b10r;
        v2f o11r = sx*b01i + cx*b10r, o11i = cx*b10i - sx*b01r;

        pr[iA] = o00r; pi[iA] = o00i;
        pr[iB] = o10r; pi[iB] = o10i;
        pr[iC] = o01r; pi[iC] = o01i;
        pr[iD] = o11r; pi[iD] = o11i;
    }
}

// Wire = packed dim (v2f halves: .x = wire0, .y = wire1), target = slot bit JT.
template<int JT>
__device__ __forceinline__ void gate_w(v2f (&pr)[16], v2f (&pi)[16],
                                       float cy, float sy, float c1, float s1,
                                       float cx, float sx)
{
    constexpr int BT = 1 << JT;
    const v2f K1 = {cy, sy};
    const v2f K2 = {-sy, cy};
    const v2f Zs = {s1, -s1};
    #pragma unroll
    for (int m = 0; m < 8; ++m) {
        int l00 = 0, mm = m;
        #pragma unroll
        for (int j = 0; j < 4; ++j)
            if (j != JT) { l00 |= (mm & 1) << j; mm >>= 1; }
        const int iA = l00, iB = l00 | BT;
        v2f Ar = pr[iA], Ai = pi[iA];   // (a00, a10) : t=0
        v2f Br = pr[iB], Bi = pi[iB];   // (a01, a11) : t=1

        // RY on wire (cross-half)
        v2f vAr = K1*Ar.xx + K2*Ar.yy;
        v2f vAi = K1*Ai.xx + K2*Ai.yy;
        v2f vBr = K1*Br.xx + K2*Br.yy;
        v2f vBi = K1*Bi.xx + K2*Bi.yy;
        // RZ on wire: half0 *= (c1 - i s1), half1 *= (c1 + i s1)
        v2f bAr = c1*vAr + Zs*vAi;
        v2f bAi = c1*vAi - Zs*vAr;
        v2f bBr = c1*vBr + Zs*vBi;
        v2f bBi = c1*vBi - Zs*vBr;
        // CNOT(w->t) + RX(w):  quad (b00=bA.x, b10=bA.y, b01=bB.x, b11=bB.y)
        v2f t1  = {bAr.x, bBr.y};   // (b00r, b11r)
        v2f t1p = {bBr.x, bAr.y};   // (b01r, b10r)
        v2f t2  = {bAi.x, bBi.y};   // (b00i, b11i)
        v2f t2p = {bBi.x, bAi.y};   // (b01i, b10i)
        pr[iA] = cx*t1  + sx*t2.yx;   // (o00r, o10r)
        pi[iA] = cx*t2  - sx*t1.yx;   // (o00i, o10i)
        pr[iB] = cx*t1p + sx*t2p.yx;  // (o01r, o11r)
        pi[iB] = cx*t2p - sx*t1p.yx;  // (o01i, o11i)
    }
}

// ---------------------------------------------------------------------------
// In-register bit swaps: exchange slot bit J with lane bit 5 (permlane32)
// or lane bit 4 (permlane16). vdst = slot-bit-0 register, src = slot-bit-1:
// vdst high lanes <-> src low lanes realizes the (j,p) transposition.
template<int J>
__device__ __forceinline__ void swap_l5(v2f (&pr)[16], v2f (&pi)[16]) {
    #pragma unroll
    for (int m = 0; m < 8; ++m) {
        int l0 = 0, mm = m;
        #pragma unroll
        for (int j = 0; j < 4; ++j)
            if (j != J) { l0 |= (mm & 1) << j; mm >>= 1; }
        const int l1 = l0 | (1 << J);
        { float a=pr[l0].x, c=pr[l1].x; asm("s_nop 1\n\tv_permlane32_swap_b32 %0, %1":"+v"(a),"+v"(c)); pr[l0].x=a; pr[l1].x=c; }
        { float a=pr[l0].y, c=pr[l1].y; asm("s_nop 1\n\tv_permlane32_swap_b32 %0, %1":"+v"(a),"+v"(c)); pr[l0].y=a; pr[l1].y=c; }
        { float a=pi[l0].x, c=pi[l1].x; asm("s_nop 1\n\tv_permlane32_swap_b32 %0, %1":"+v"(a),"+v"(c)); pi[l0].x=a; pi[l1].x=c; }
        { float a=pi[l0].y, c=pi[l1].y; asm("s_nop 1\n\tv_permlane32_swap_b32 %0, %1":"+v"(a),"+v"(c)); pi[l0].y=a; pi[l1].y=c; }
    }
}

template<int J>
__device__ __forceinline__ void swap_l4(v2f (&pr)[16], v2f (&pi)[16]) {
    #pragma unroll
    for (int m = 0; m < 8; ++m) {
        int l0 = 0, mm = m;
        #pragma unroll
        for (int j = 0; j < 4; ++j)
            if (j != J) { l0 |= (mm & 1) << j; mm >>= 1; }
        const int l1 = l0 | (1 << J);
        { float a=pr[l0].x, c=pr[l1].x; asm("s_nop 1\n\tv_permlane16_swap_b32 %0, %1":"+v"(a),"+v"(c)); pr[l0].x=a; pr[l1].x=c; }
        { float a=pr[l0].y, c=pr[l1].y; asm("s_nop 1\n\tv_permlane16_swap_b32 %0, %1":"+v"(a),"+v"(c)); pr[l0].y=a; pr[l1].y=c; }
        { float a=pi[l0].x, c=pi[l1].x; asm("s_nop 1\n\tv_permlane16_swap_b32 %0, %1":"+v"(a),"+v"(c)); pi[l0].x=a; pi[l1].x=c; }
        { float a=pi[l0].y, c=pi[l1].y; asm("s_nop 1\n\tv_permlane16_swap_b32 %0, %1":"+v"(a),"+v"(c)); pi[l0].y=a; pi[l1].y=c; }
    }
}

// ---------------------------------------------------------------------------
// LDS round trips. A0..A3 = global positions of slot bits, PP = packed bit.
// sb = swzc(scatter of t); per-element address = sb ^ swzc(off) (1 XOR).
template<int A0,int A1,int A2,int A3,int PP>
__device__ __forceinline__ void lds_load(const float* re, const float* im,
                                         v2f (&pr)[16], v2f (&pi)[16], int sb) {
    #pragma unroll
    for (int l = 0; l < 16; ++l) {
        const int off = ((l & 1) << A0) | (((l >> 1) & 1) << A1) |
                        (((l >> 2) & 1) << A2) | (((l >> 3) & 1) << A3);
        const int s0 = sb ^ swzc(off);
        const int s1 = sb ^ swzc(off | (1 << PP));
        pr[l] = v2f{re[s0], re[s1]};
        pi[l] = v2f{im[s0], im[s1]};
    }
}

template<int A0,int A1,int A2,int A3,int PP>
__device__ __forceinline__ void lds_store(float* re, float* im,
                                          const v2f (&pr)[16], const v2f (&pi)[16], int sb) {
    #pragma unroll
    for (int l = 0; l < 16; ++l) {
        const int off = ((l & 1) << A0) | (((l >> 1) & 1) << A1) |
                        (((l >> 2) & 1) << A2) | (((l >> 3) & 1) << A3);
        const int s0 = sb ^ swzc(off);
        const int s1 = sb ^ swzc(off | (1 << PP));
        re[s0] = pr[l].x; re[s1] = pr[l].y;
        im[s0] = pi[l].x; im[s1] = pi[l].y;
    }
}

__global__ __launch_bounds__(NT, 1) void qsim(const float* __restrict__ state,
                                              const float* __restrict__ params,
                                              const float* __restrict__ head_w,
                                              const float* __restrict__ head_b,
                                              float* __restrict__ out)
{
    __shared__ float re[DIM];           // 64 KiB
    __shared__ float im[DIM];           // 64 KiB
    __shared__ float2 csv[NW * 3 * 2];  // (cos,sin) of half-angles, 84 gates
    __shared__ float partial[NT / 64];

    const int t = threadIdx.x;
    const int b = blockIdx.x;

    v2f pr[16], pi[16];

    // Phase 1 layout: slots A=[9,10,11,12], P=13; t: l=[0,1,2,3], L4=7, L5=8,
    // W=[4,5,6]. Load from HBM (16 consecutive floats per 16 lanes).
    const float* __restrict__ sp = state + (size_t)b * DIM;
    const int tb1 = scat9<0,1,2,3,7,8,4,5,6>(t);
    #pragma unroll
    for (int l = 0; l < 16; ++l) {
        const int off = ((l & 1) << 9) | (((l >> 1) & 1) << 10) |
                        (((l >> 2) & 1) << 11) | (((l >> 3) & 1) << 12);
        pr[l] = v2f{sp[tb1 | off], sp[tb1 | off | (1 << 13)]};
        pi[l] = v2f{0.0f, 0.0f};
    }

    if (t < NW * 3 * 2) {
        float sv, cv;
        sincosf(params[t] * 0.5f, &sv, &cv);
        csv[t] = make_float2(cv, sv);
    }
    __syncthreads();

#define GU(JW, JT, G) do {                                              \
        float2 vy = csv[(G)*3+0], vz = csv[(G)*3+1], vx = csv[(G)*3+2]; \
        gate_u<JW, JT>(pr, pi, vy.x, vy.y, vz.x, vz.y, vx.x, vx.y);     \
    } while (0)
#define GW(JT, G) do {                                                  \
        float2 vy = csv[(G)*3+0], vz = csv[(G)*3+1], vx = csv[(G)*3+2]; \
        gate_w<JT>(pr, pi, vy.x, vy.y, vz.x, vz.y, vx.x, vx.y);         \
    } while (0)

    // ---- Phase 1: gates 0-5 (wires 13..8 as bit pairs (13,12)..(8,7)) ----
    // A=[9,10,11,12], P=13
    GW(3, 0);            // (13,12)
    GU(3, 2, 1);         // (12,11)
    GU(2, 1, 2);         // (11,10)
    GU(1, 0, 3);         // (10,9)
    swap_l5<3>(pr, pi);  // slot3(12) <-> lane5(8): A=[9,10,11,8]
    GU(0, 3, 4);         // (9,8)
    swap_l4<0>(pr, pi);  // slot0(9) <-> lane4(7): A=[7,10,11,8]
    GU(3, 0, 5);         // (8,7)
    lds_store<7,10,11,8,13>(re, im, pr, pi, swzc(scat9<0,1,2,3,9,12,4,5,6>(t)));
    __syncthreads();

    // ---- Phase 2: gates 6-11 ---- A=[3,4,5,6], P=7; l=[0,8,9,11], L4=1, L5=2
    lds_load<3,4,5,6,7>(re, im, pr, pi, swzc(scat9<0,8,9,11,1,2,10,12,13>(t)));
    GW(3, 6);            // (7,6)
    GU(3, 2, 7);         // (6,5)
    GU(2, 1, 8);         // (5,4)
    GU(1, 0, 9);         // (4,3)
    swap_l5<3>(pr, pi);  // slot3(6) <-> lane5(2): A=[3,4,5,2]
    GU(0, 3, 10);        // (3,2)
    swap_l4<2>(pr, pi);  // slot2(5) <-> lane4(1): A=[3,4,1,2]
    GU(3, 2, 11);        // (2,1)
    lds_store<3,4,1,2,7>(re, im, pr, pi, swzc(scat9<0,8,9,11,5,6,10,12,13>(t)));
    __syncthreads();

    // ---- Phase 3: gates 12-17 ---- A=[0,13,12,11], P=1; l=[2,5,6,3], L4=9, L5=10
    lds_load<0,13,12,11,1>(re, im, pr, pi, swzc(scat9<2,5,6,3,9,10,4,7,8>(t)));
    GW(0, 12);           // (1,0)
    GU(0, 1, 13);        // (0,13)
    GU(1, 2, 14);        // (13,12)
    GU(2, 3, 15);        // (12,11)
    swap_l5<1>(pr, pi);  // slot1(13) <-> lane5(10): A=[0,10,12,11]
    GU(3, 1, 16);        // (11,10)
    swap_l4<0>(pr, pi);  // slot0(0) <-> lane4(9): A=[9,10,12,11]
    GU(1, 0, 17);        // (10,9)
    lds_store<9,10,12,11,1>(re, im, pr, pi, swzc(scat9<2,5,6,3,0,13,4,7,8>(t)));
    __syncthreads();

    // ---- Phase 4: gates 18-23 ---- A=[8,7,6,5], P=9; l=[0,1,2,13], L4=3, L5=4
    lds_load<8,7,6,5,9>(re, im, pr, pi, swzc(scat9<0,1,2,13,3,4,10,11,12>(t)));
    GW(0, 18);           // (9,8)
    GU(0, 1, 19);        // (8,7)
    GU(1, 2, 20);        // (7,6)
    GU(2, 3, 21);        // (6,5)
    swap_l5<0>(pr, pi);  // slot0(8) <-> lane5(4): A=[4,7,6,5]
    GU(3, 0, 22);        // (5,4)
    swap_l4<1>(pr, pi);  // slot1(7) <-> lane4(3): A=[4,3,6,5]
    GU(0, 1, 23);        // (4,3)
    lds_store<4,3,6,5,9>(re, im, pr, pi, swzc(scat9<0,1,2,13,7,8,10,11,12>(t)));
    __syncthreads();

    // ---- Phase 5: gates 24-27 ---- A=[2,1,0,13], P=3; l=[4,5,6,7]
    lds_load<2,1,0,13,3>(re, im, pr, pi, swzc(scat9<4,5,6,7,8,9,10,11,12>(t)));
    GW(0, 24);           // (3,2)
    GU(0, 1, 25);        // (2,1)
    GU(1, 2, 26);        // (1,0)
    GU(2, 3, 27);        // (0,13)

    // ---- Epilogue (from registers) ----
    // P5 positions: slot0->2, slot1->1, slot2->0, slot3->13, P->3,
    // t0..t8 -> [4,5,6,7,8,9,10,11,12]  (wire w = 13 - pos)
    float hw[NW];
    #pragma unroll
    for (int w = 0; w < NW; ++w) hw[w] = head_w[w];

    float gbase = 0.0f;
    gbase += (t & 1)   ? -hw[9] : hw[9];
    gbase += (t & 2)   ? -hw[8] : hw[8];
    gbase += (t & 4)   ? -hw[7] : hw[7];
    gbase += (t & 8)   ? -hw[6] : hw[6];
    gbase += (t & 16)  ? -hw[5] : hw[5];
    gbase += (t & 32)  ? -hw[4] : hw[4];
    gbase += (t & 64)  ? -hw[3] : hw[3];
    gbase += (t & 128) ? -hw[2] : hw[2];
    gbase += (t & 256) ? -hw[1] : hw[1];

    v2f acc2 = {0.0f, 0.0f};
    #pragma unroll
    for (int l = 0; l < 16; ++l) {
        float g = gbase;
        g += (l & 1) ? -hw[11] : hw[11];
        g += (l & 2) ? -hw[12] : hw[12];
        g += (l & 4) ? -hw[13] : hw[13];
        g += (l & 8) ? -hw[0]  : hw[0];
        v2f gv = {g + hw[10], g - hw[10]};
        acc2 += (pr[l]*pr[l] + pi[l]*pi[l]) * gv;
    }
    float acc = acc2.x + acc2.y;

    #pragma unroll
    for (int off = 32; off > 0; off >>= 1) acc += __shfl_down(acc, off);
    if ((t & 63) == 0) partial[t >> 6] = acc;
    __syncthreads();
    if (t == 0) {
        float tot = 0.0f;
        #pragma unroll
        for (int k = 0; k < NT / 64; ++k) tot += partial[k];
        out[b] = tot + head_b[0];
    }
#undef GU
#undef GW
}

extern "C" void kernel_launch(void* const* d_in, const int* in_sizes, int n_in,
                              void* d_out, int out_size, void* d_ws, size_t ws_size,
                              hipStream_t stream) {
    const float* state  = (const float*)d_in[0];
    const float* params = (const float*)d_in[1];
    const float* head_w = (const float*)d_in[2];
    const float* head_b = (const float*)d_in[3];
    float* outp = (float*)d_out;
    qsim<<<BATCH, NT, 0, stream>>>(state, params, head_w, head_b, outp);
}

// Round 5
// 36.742 us; speedup vs baseline: 1.0224x; 1.0224x over previous
//
#include <hip/hip_runtime.h>
#include <math.h>

typedef float v2f __attribute__((ext_vector_type(2)));

constexpr int NW = 14;
constexpr int DIM = 1 << NW;      // 16384
constexpr int BATCH = 256;
constexpr int NT = 1024;          // 16 waves; 16 amps/thread as 8 v2f pairs

// Bank swizzle on float2 (8B) units: fold bits 4..7, 8..11, 12..13 into the
// low-4 bank-pair bits. XOR-linear: swz2(a^b)=swz2(a)^swz2(b).
// Verified per phase: lane-bit images have rank 4 => 4 lanes/bank-pair (min).
__device__ __host__ constexpr int swz2(int i) {
    return i ^ ((i >> 4) & 15) ^ ((i >> 8) & 15) ^ ((i >> 12) & 3);
}

// Scatter thread id t (10 bits) to global bit positions.
// Q0..Q5 = lane bits 0..5, Q6..Q9 = wave bits.
template<int Q0,int Q1,int Q2,int Q3,int Q4,int Q5,int Q6,int Q7,int Q8,int Q9>
__device__ __forceinline__ int scat10(int t) {
    return ((t & 1) << Q0) | (((t >> 1) & 1) << Q1) | (((t >> 2) & 1) << Q2) |
           (((t >> 3) & 1) << Q3) | (((t >> 4) & 1) << Q4) | (((t >> 5) & 1) << Q5) |
           (((t >> 6) & 1) << Q6) | (((t >> 7) & 1) << Q7) | (((t >> 8) & 1) << Q8) |
           (((t >> 9) & 1) << Q9);
}

// ---------------------------------------------------------------------------
// Uniform packed gate: wire = slot bit JW, target = slot bit JT (3 slot bits;
// packed dim is a spectator). One spectator slot bit -> 2 quads.
template<int JW, int JT>
__device__ __forceinline__ void gate_u(v2f (&pr)[8], v2f (&pi)[8],
                                       float cy, float sy, float c1, float s1,
                                       float cx, float sx)
{
    constexpr int BW = 1 << JW, BT = 1 << JT, JF = 3 - JW - JT;
    #pragma unroll
    for (int m = 0; m < 2; ++m) {
        const int l00 = m << JF;
        const int iA = l00, iB = l00 | BW, iC = l00 | BT, iD = l00 | BW | BT;

        v2f a00r = pr[iA], a00i = pi[iA];
        v2f a10r = pr[iB], a10i = pi[iB];
        v2f a01r = pr[iC], a01i = pi[iC];
        v2f a11r = pr[iD], a11i = pi[iD];

        v2f v0r = cy*a00r - sy*a10r, v0i = cy*a00i - sy*a10i;
        v2f v1r = sy*a00r + cy*a10r, v1i = sy*a00i + cy*a10i;
        v2f u0r = cy*a01r - sy*a11r, u0i = cy*a01i - sy*a11i;
        v2f u1r = sy*a01r + cy*a11r, u1i = sy*a01i + cy*a11i;

        v2f b00r = c1*v0r + s1*v0i, b00i = c1*v0i - s1*v0r;
        v2f b10r = c1*v1r - s1*v1i, b10i = c1*v1i + s1*v1r;
        v2f b01r = c1*u0r + s1*u0i, b01i = c1*u0i - s1*u0r;
        v2f b11r = c1*u1r - s1*u1i, b11i = c1*u1i + s1*u1r;

        v2f o00r = cx*b00r + sx*b11i, o00i = cx*b00i - sx*b11r;
        v2f o10r = sx*b00i + cx*b11r, o10i = cx*b11i - sx*b00r;
        v2f o01r = cx*b01r + sx*b10i, o01i = cx*b01i - sx*b10r;
        v2f o11r = sx*b01i + cx*b10r, o11i = cx*b10i - sx*b01r;

        pr[iA] = o00r; pi[iA] = o00i;
        pr[iB] = o10r; pi[iB] = o10i;
        pr[iC] = o01r; pi[iC] = o01i;
        pr[iD] = o11r; pi[iD] = o11i;
    }
}

// Wire = packed dim (.x = wire0, .y = wire1), target = slot bit JT.
template<int JT>
__device__ __forceinline__ void gate_w(v2f (&pr)[8], v2f (&pi)[8],
                                       float cy, float sy, float c1, float s1,
                                       float cx, float sx)
{
    constexpr int BT = 1 << JT;
    constexpr int jA = (JT == 0) ? 1 : 0, jB = (JT == 2) ? 1 : 2;
    const v2f K1 = {cy, sy};
    const v2f K2 = {-sy, cy};
    const v2f Zs = {s1, -s1};
    #pragma unroll
    for (int m = 0; m < 4; ++m) {
        const int l00 = ((m & 1) << jA) | (((m >> 1) & 1) << jB);
        const int iA = l00, iB = l00 | BT;
        v2f Ar = pr[iA], Ai = pi[iA];   // (a00, a10) : t=0
        v2f Br = pr[iB], Bi = pi[iB];   // (a01, a11) : t=1

        v2f vAr = K1*Ar.xx + K2*Ar.yy;
        v2f vAi = K1*Ai.xx + K2*Ai.yy;
        v2f vBr = K1*Br.xx + K2*Br.yy;
        v2f vBi = K1*Bi.xx + K2*Bi.yy;

        v2f bAr = c1*vAr + Zs*vAi;
        v2f bAi = c1*vAi - Zs*vAr;
        v2f bBr = c1*vBr + Zs*vBi;
        v2f bBi = c1*vBi - Zs*vBr;

        v2f t1  = {bAr.x, bBr.y};   // (b00r, b11r)
        v2f t1p = {bBr.x, bAr.y};   // (b01r, b10r)
        v2f t2  = {bAi.x, bBi.y};   // (b00i, b11i)
        v2f t2p = {bBi.x, bAi.y};   // (b01i, b10i)
        pr[iA] = cx*t1  + sx*t2.yx;   // (o00r, o10r)
        pi[iA] = cx*t2  - sx*t1.yx;   // (o00i, o10i)
        pr[iB] = cx*t1p + sx*t2p.yx;  // (o01r, o11r)
        pi[iB] = cx*t2p - sx*t1p.yx;  // (o01i, o11i)
    }
}

// ---------------------------------------------------------------------------
// Exchange slot bit J with lane bit 5 / lane bit 4 (same proven R4 pattern).
template<int J>
__device__ __forceinline__ void swap_l5(v2f (&pr)[8], v2f (&pi)[8]) {
    constexpr int jA = (J == 0) ? 1 : 0, jB = (J == 2) ? 1 : 2;
    #pragma unroll
    for (int m = 0; m < 4; ++m) {
        const int l0 = ((m & 1) << jA) | (((m >> 1) & 1) << jB);
        const int l1 = l0 | (1 << J);
        { float a=pr[l0].x, c=pr[l1].x; asm("s_nop 1\n\tv_permlane32_swap_b32 %0, %1":"+v"(a),"+v"(c)); pr[l0].x=a; pr[l1].x=c; }
        { float a=pr[l0].y, c=pr[l1].y; asm("s_nop 1\n\tv_permlane32_swap_b32 %0, %1":"+v"(a),"+v"(c)); pr[l0].y=a; pr[l1].y=c; }
        { float a=pi[l0].x, c=pi[l1].x; asm("s_nop 1\n\tv_permlane32_swap_b32 %0, %1":"+v"(a),"+v"(c)); pi[l0].x=a; pi[l1].x=c; }
        { float a=pi[l0].y, c=pi[l1].y; asm("s_nop 1\n\tv_permlane32_swap_b32 %0, %1":"+v"(a),"+v"(c)); pi[l0].y=a; pi[l1].y=c; }
    }
}

template<int J>
__device__ __forceinline__ void swap_l4(v2f (&pr)[8], v2f (&pi)[8]) {
    constexpr int jA = (J == 0) ? 1 : 0, jB = (J == 2) ? 1 : 2;
    #pragma unroll
    for (int m = 0; m < 4; ++m) {
        const int l0 = ((m & 1) << jA) | (((m >> 1) & 1) << jB);
        const int l1 = l0 | (1 << J);
        { float a=pr[l0].x, c=pr[l1].x; asm("s_nop 1\n\tv_permlane16_swap_b32 %0, %1":"+v"(a),"+v"(c)); pr[l0].x=a; pr[l1].x=c; }
        { float a=pr[l0].y, c=pr[l1].y; asm("s_nop 1\n\tv_permlane16_swap_b32 %0, %1":"+v"(a),"+v"(c)); pr[l0].y=a; pr[l1].y=c; }
        { float a=pi[l0].x, c=pi[l1].x; asm("s_nop 1\n\tv_permlane16_swap_b32 %0, %1":"+v"(a),"+v"(c)); pi[l0].x=a; pi[l1].x=c; }
        { float a=pi[l0].y, c=pi[l1].y; asm("s_nop 1\n\tv_permlane16_swap_b32 %0, %1":"+v"(a),"+v"(c)); pi[l0].y=a; pi[l1].y=c; }
    }
}

// ---------------------------------------------------------------------------
// LDS round trips on float2 amps (b64 per amp). S0,S1,S2 = global positions
// of reg-index bits, PP = packed-bit position. sb = swz2(scatter of t).
template<int S0,int S1,int S2,int PP>
__device__ __forceinline__ void lds_store(float2* cs,
                                          const v2f (&pr)[8], const v2f (&pi)[8], int sb) {
    #pragma unroll
    for (int k = 0; k < 8; ++k) {
        const int off = ((k & 1) << S0) | (((k >> 1) & 1) << S1) | (((k >> 2) & 1) << S2);
        cs[sb ^ swz2(off)]             = float2{pr[k].x, pi[k].x};
        cs[sb ^ swz2(off | (1 << PP))] = float2{pr[k].y, pi[k].y};
    }
}

template<int S0,int S1,int S2,int PP>
__device__ __forceinline__ void lds_load(const float2* cs,
                                         v2f (&pr)[8], v2f (&pi)[8], int sb) {
    #pragma unroll
    for (int k = 0; k < 8; ++k) {
        const int off = ((k & 1) << S0) | (((k >> 1) & 1) << S1) | (((k >> 2) & 1) << S2);
        const float2 a0 = cs[sb ^ swz2(off)];
        const float2 a1 = cs[sb ^ swz2(off | (1 << PP))];
        pr[k] = v2f{a0.x, a1.x};
        pi[k] = v2f{a0.y, a1.y};
    }
}

__global__ __launch_bounds__(NT, 1) void qsim(const float* __restrict__ state,
                                              const float* __restrict__ params,
                                              const float* __restrict__ head_w,
                                              const float* __restrict__ head_b,
                                              float* __restrict__ out)
{
    __shared__ float2 cs[DIM];          // 128 KiB (re,im interleaved)
    __shared__ float2 csv[NW * 3 * 2];  // (cos,sin) of half-angles, 84 gates
    __shared__ float partial[NT / 64];

    const int t = threadIdx.x;
    const int b = blockIdx.x;

    v2f pr[8], pi[8];

    // Phase A layout: P=13, S=[10,11,12], L=[0,1,2,3,8,9], W=[4,5,6,7].
    // HBM load: per (k,h): lanes cover 4 x 64B contiguous segments. im = 0.
    const float* __restrict__ sp = state + (size_t)b * DIM;
    const int tbA = scat10<0,1,2,3,8,9,4,5,6,7>(t);
    #pragma unroll
    for (int k = 0; k < 8; ++k) {
        const int base = tbA | (k << 10);
        pr[k] = v2f{sp[base], sp[base | (1 << 13)]};
        pi[k] = v2f{0.0f, 0.0f};
    }

    if (t < NW * 3 * 2) {
        float sv, cv;
        sincosf(params[t] * 0.5f, &sv, &cv);
        csv[t] = make_float2(cv, sv);
    }
    __syncthreads();

#define GU(JW, JT, G) do {                                              \
        float2 vy = csv[(G)*3+0], vz = csv[(G)*3+1], vx = csv[(G)*3+2]; \
        gate_u<JW, JT>(pr, pi, vy.x, vy.y, vz.x, vz.y, vx.x, vx.y);     \
    } while (0)
#define GW(JT, G) do {                                                  \
        float2 vy = csv[(G)*3+0], vz = csv[(G)*3+1], vx = csv[(G)*3+2]; \
        gate_w<JT>(pr, pi, vy.x, vy.y, vz.x, vz.y, vx.x, vx.y);         \
    } while (0)

    // ---- Phase A: gates 0-4, bits (13,12)..(9,8) ----
    GW(2, 0);            // (13,12)
    GU(2, 1, 1);         // (12,11)
    GU(1, 0, 2);         // (11,10)
    swap_l5<2>(pr, pi);  // S2(12,done) <-> L5(9): S=[10,11,9], L5->12
    GU(0, 2, 3);         // (10,9)
    swap_l4<1>(pr, pi);  // S1(11,done) <-> L4(8): S=[10,8,9], L4->11
    GU(2, 1, 4);         // (9,8)
    // End-A: P=13, S=[10,8,9], L=[0,1,2,3,11,12], W=[4,5,6,7]
    lds_store<10,8,9,13>(cs, pr, pi, swz2(scat10<0,1,2,3,11,12,4,5,6,7>(t)));
    __syncthreads();

    // ---- Phase B: gates 5-9, bits (8,7)..(4,3) ----
    // Layout: P=8, S=[5,6,7], L=[0,1,2,9,3,4], W=[10,11,12,13]
    const int sbB = swz2(scat10<0,1,2,9,3,4,10,11,12,13>(t));
    lds_load<5,6,7,8>(cs, pr, pi, sbB);
    GW(2, 5);            // (8,7)
    GU(2, 1, 6);         // (7,6)
    GU(1, 0, 7);         // (6,5)
    swap_l5<2>(pr, pi);  // S2(7) <-> L5(4): S=[5,6,4], L5->7
    GU(0, 2, 8);         // (5,4)
    swap_l4<1>(pr, pi);  // S1(6) <-> L4(3): S=[5,3,4], L4->6
    GU(2, 1, 9);         // (4,3)
    // End-B: P=8, S=[5,3,4], L=[0,1,2,9,6,7], W=[10,11,12,13]
    lds_store<5,3,4,8>(cs, pr, pi, swz2(scat10<0,1,2,9,6,7,10,11,12,13>(t)));
    __syncthreads();

    // ---- Phase C: gates 10-13, bits (3,2),(2,1),(1,0),(0,13) ----
    // Layout: P=3, S=[0,1,2], L=[4,5,6,7,9,13], W=[8,10,11,12]
    const int sbC = swz2(scat10<4,5,6,7,9,13,8,10,11,12>(t));
    lds_load<0,1,2,3>(cs, pr, pi, sbC);
    GW(2, 10);           // (3,2)
    GU(2, 1, 11);        // (2,1)
    GU(1, 0, 12);        // (1,0)
    swap_l5<2>(pr, pi);  // S2(2) <-> L5(13): S=[0,1,13], L5->2
    GU(0, 2, 13);        // (0,13)
    // End-C: P=3, S=[0,1,13], L=[4,5,6,7,9,2], W=[8,10,11,12]
    lds_store<0,1,13,3>(cs, pr, pi, swz2(scat10<4,5,6,7,9,2,8,10,11,12>(t)));
    __syncthreads();

    // ---- Phase D: gates 14-18 (layer 2, same window as A) ----
    lds_load<10,11,12,13>(cs, pr, pi, swz2(tbA));
    GW(2, 14);
    GU(2, 1, 15);
    GU(1, 0, 16);
    swap_l5<2>(pr, pi);
    GU(0, 2, 17);
    swap_l4<1>(pr, pi);
    GU(2, 1, 18);
    lds_store<10,8,9,13>(cs, pr, pi, swz2(scat10<0,1,2,3,11,12,4,5,6,7>(t)));
    __syncthreads();

    // ---- Phase E: gates 19-23 (same window as B) ----
    lds_load<5,6,7,8>(cs, pr, pi, sbB);
    GW(2, 19);
    GU(2, 1, 20);
    GU(1, 0, 21);
    swap_l5<2>(pr, pi);
    GU(0, 2, 22);
    swap_l4<1>(pr, pi);
    GU(2, 1, 23);
    lds_store<5,3,4,8>(cs, pr, pi, swz2(scat10<0,1,2,9,6,7,10,11,12,13>(t)));
    __syncthreads();

    // ---- Phase F: gates 24-27 (same window as C); epilogue from regs ----
    lds_load<0,1,2,3>(cs, pr, pi, sbC);
    GW(2, 24);
    GU(2, 1, 25);
    GU(1, 0, 26);
    swap_l5<2>(pr, pi);
    GU(0, 2, 27);

    // ---- Epilogue ----
    // End-F roles: k0->bit0, k1->bit1, k2->bit13, h->bit3;
    // lanes l0->4,l1->5,l2->6,l3->7,l4->9,l5->2; waves t6->8,t7->10,t8->11,t9->12.
    // Wire w = 13 - bit position; g(i) = sum_p hw[13-p]*(1-2*bit_p(i)).
    float hw[NW];
    #pragma unroll
    for (int w = 0; w < NW; ++w) hw[w] = head_w[w];

    float gbase = 0.0f;
    gbase += (t & 1)   ? -hw[9]  : hw[9];
    gbase += (t & 2)   ? -hw[8]  : hw[8];
    gbase += (t & 4)   ? -hw[7]  : hw[7];
    gbase += (t & 8)   ? -hw[6]  : hw[6];
    gbase += (t & 16)  ? -hw[4]  : hw[4];
    gbase += (t & 32)  ? -hw[11] : hw[11];
    gbase += (t & 64)  ? -hw[5]  : hw[5];
    gbase += (t & 128) ? -hw[3]  : hw[3];
    gbase += (t & 256) ? -hw[2]  : hw[2];
    gbase += (t & 512) ? -hw[1]  : hw[1];

    v2f acc2 = {0.0f, 0.0f};
    #pragma unroll
    for (int k = 0; k < 8; ++k) {
        float g = gbase;
        g += (k & 1) ? -hw[13] : hw[13];
        g += (k & 2) ? -hw[12] : hw[12];
        g += (k & 4) ? -hw[0]  : hw[0];
        v2f gv = {g + hw[10], g - hw[10]};
        acc2 += (pr[k]*pr[k] + pi[k]*pi[k]) * gv;
    }
    float acc = acc2.x + acc2.y;

    #pragma unroll
    for (int off = 32; off > 0; off >>= 1) acc += __shfl_down(acc, off);
    if ((t & 63) == 0) partial[t >> 6] = acc;
    __syncthreads();
    if (t == 0) {
        float tot = 0.0f;
        #pragma unroll
        for (int k = 0; k < NT / 64; ++k) tot += partial[k];
        out[b] = tot + head_b[0];
    }
#undef GU
#undef GW
}

extern "C" void kernel_launch(void* const* d_in, const int* in_sizes, int n_in,
                              void* d_out, int out_size, void* d_ws, size_t ws_size,
                              hipStream_t stream) {
    const float* state  = (const float*)d_in[0];
    const float* params = (const float*)d_in[1];
    const float* head_w = (const float*)d_in[2];
    const float* head_b = (const float*)d_in[3];
    float* outp = (float*)d_out;
    qsim<<<BATCH, NT, 0, stream>>>(state, params, head_w, head_b, outp);
}